// Round 11
// baseline (963.327 us; speedup 1.0000x reference)
//
#include <hip/hip_runtime.h>

// Problem dims (fixed by the reference setup)
#define Bn 8
#define Sn 2048
#define Dn 512
#define Gn 4
#define Cn 2048
#define DGn 128
#define Nn 16384  // B*S

// d_out layout (flat fp32, reference return order)
#define OFF_Q    0u        // quantize_st  [8,2048,512]  = 8388608
#define OFF_IND  8388608u  // ind_out      [8,2048,4]    = 65536 (float-encoded ints)
#define OFF_LOSS 8454144u  // commit_loss  scalar
#define OFF_CS   8454145u  // new_cluster_size [4,2048]  = 8192
#define OFF_AVG  8462337u  // new_embed_avg [4,2048,128] = 1048576
#define OFF_EMB  9510913u  // new_embed     [4,2048,128] = 1048576 (first 8192 hold ||E||^2 until finalize)

typedef __attribute__((ext_vector_type(8)))  short bf16x8;
typedef __attribute__((ext_vector_type(16))) float f32x16;

// fp32 -> bf16 bits, round-to-nearest-even
__device__ __forceinline__ unsigned bfbits(float x) {
    unsigned u = __float_as_uint(x);
    return (u + 0x7FFFu + ((u >> 16) & 1u)) & 0xFFFF0000u;
}
// exact-ish 3-way bf16 decomposition: a = h + m + l + O(2^-27 |a|)
__device__ __forceinline__ void split3(float a, short &sh, short &sm, short &sl) {
    unsigned hb = bfbits(a); float hf = __uint_as_float(hb);
    float r  = a - hf;                 // exact (Sterbenz)
    unsigned mb = bfbits(r); float mf = __uint_as_float(mb);
    float r2 = r - mf;                 // exact
    unsigned lb = bfbits(r2);
    sh = (short)(hb >> 16); sm = (short)(mb >> 16); sl = (short)(lb >> 16);
}

// one wave per code row: ||E[g,c]||^2 -> stash at OFF_EMB (overwritten by finalize).
// Also zeroes the loss scalar (no vq_init kernel anymore).
__global__ void vq_enorm(const float* __restrict__ embed,
                         float* __restrict__ out) {
    int gid  = blockIdx.x * 256 + threadIdx.x;
    int wave = gid >> 6;
    int lane = gid & 63;
    if (gid == 0) out[OFF_LOSS] = 0.0f;
    const float* row = embed + (size_t)wave * DGn;
    float a = row[lane], b = row[lane + 64];
    float v = fmaf(a, a, b * b);
    #pragma unroll
    for (int off = 32; off; off >>= 1) v += __shfl_xor(v, off, 64);
    if (lane == 0) out[OFF_EMB + wave] = v;
}

// frag-layout LDS indices (units: shorts; each frag slot = 16B = 8 bf16)
#define IA(mt,v,ks,lane) (((((mt)*3+(v))*8+(ks))*64+(lane))*8)
#define IB(v,cst,lane)   ((((v)*8+(cst))*64+(lane))*8)

// MFMA main (verified R9/R10): block = (g, 128-token tile). 512 thr = 8 waves
// (2m x 4c), wave = 64m x 64c via 2x2 mfma_f32_32x32x16_bf16 frags. bf16
// split-3, 6 passes/K-step -> dot exact to ~2^-27. c swept in 8 tiles of 256.
// Writes OFF_IND only (cluster-size moved to vq_code).
__launch_bounds__(512, 1)
__global__ void vq_main(const float* __restrict__ x,
                        const float* __restrict__ embed,
                        float* __restrict__ out) {
    __shared__ short A_sh[49152];   // [4 mt][3 v][8 ks][64 lane][8] = 96 KB
    __shared__ short B0_sh[12288];  // [3 v][8 cst][64 lane][8]     = 24 KB
    __shared__ float S_sh[8704];    // scores [128][68]              = 34 KB
    short* const B1_sh = (short*)S_sh;  // B double-buffer aliases S

    const int t  = threadIdx.x;
    const int l  = t & 63;
    const int w  = t >> 6;
    const int wm = w >> 2, wc = w & 3;
    const int g  = blockIdx.x >> 7;
    const int n0 = (blockIdx.x & 127) * 128;

    const float* eg = embed + (size_t)g * Cn * DGn;
    const float* enorm_g = out + OFF_EMB + g * Cn;

    // ---- stage A (128m x 128k, 3 versions) directly in frag layout ----
    {
        const int m  = t >> 2, q = t & 3;
        const int mt = m >> 5;
        const float* xr = x + (size_t)(n0 + m) * Dn + g * DGn;
        #pragma unroll
        for (int j = 0; j < 8; ++j) {
            const int k = q * 32 + j * 4;
            float4 v = *(const float4*)(xr + k);
            short h0,h1,h2,h3, p0,p1,p2,p3, q0,q1,q2,q3;
            split3(v.x, h0, p0, q0); split3(v.y, h1, p1, q1);
            split3(v.z, h2, p2, q2); split3(v.w, h3, p3, q3);
            const int lane_ = (m & 31) + ((k >> 3) & 1) * 32;
            const int ks = k >> 4, sl0 = k & 7;    // sl0 in {0,4}
            short4 hv; hv.x=h0; hv.y=h1; hv.z=h2; hv.w=h3;
            short4 mv; mv.x=p0; mv.y=p1; mv.z=p2; mv.w=p3;
            short4 lv; lv.x=q0; lv.y=q1; lv.z=q2; lv.w=q3;
            *(short4*)&A_sh[IA(mt,0,ks,lane_) + sl0] = hv;
            *(short4*)&A_sh[IA(mt,1,ks,lane_) + sl0] = mv;
            *(short4*)&A_sh[IA(mt,2,ks,lane_) + sl0] = lv;
        }
    }
    // ---- prologue: stage B (ct=0, ks=0) into B0 ----
    {
        const float* er = eg + (size_t)(t >> 1) * DGn + (t & 1) * 8;
        float4 e0 = *(const float4*)(er);
        float4 e1 = *(const float4*)(er + 4);
        float vals[8] = {e0.x,e0.y,e0.z,e0.w,e1.x,e1.y,e1.z,e1.w};
        short hh[8], mm_[8], ll[8];
        #pragma unroll
        for (int i = 0; i < 8; ++i) split3(vals[i], hh[i], mm_[i], ll[i]);
        const int cst = (t >> 1) >> 5, lb_ = ((t >> 1) & 31) + ((t & 1) << 5);
        bf16x8 H, M, L;
        #pragma unroll
        for (int i = 0; i < 8; ++i) { H[i]=hh[i]; M[i]=mm_[i]; L[i]=ll[i]; }
        *(bf16x8*)&B0_sh[IB(0,cst,lb_)] = H;
        *(bf16x8*)&B0_sh[IB(1,cst,lb_)] = M;
        *(bf16x8*)&B0_sh[IB(2,cst,lb_)] = L;
    }
    __syncthreads();

    f32x16 acc00, acc01, acc10, acc11;  // acc[mf][cf]
    #pragma unroll
    for (int r = 0; r < 16; ++r) { acc00[r]=0.f; acc01[r]=0.f; acc10[r]=0.f; acc11[r]=0.f; }

    float bv = -3.4e38f; int bi = 0;    // per-thread running argmax (index-tiebreak)

    const int mt0 = wm*2, mt1 = wm*2 + 1;
    const int cst0 = wc*2, cst1 = wc*2 + 1;

    for (int s = 0; s < 64; ++s) {       // s = ct*8 + ks; ct-tile = 256 c
        const int ct = s >> 3, ks = s & 7;
        const short* curB = (s & 1) ? B1_sh : B0_sh;

        // T14: issue next-stage global loads before compute
        float4 e0n, e1n;
        if (s < 63) {
            const int s1 = s + 1, ct1 = s1 >> 3, ks1 = s1 & 7;
            const float* er = eg + (size_t)(ct1*256 + (t >> 1)) * DGn + ks1*16 + (t & 1)*8;
            e0n = *(const float4*)(er);
            e1n = *(const float4*)(er + 4);
        }

        bf16x8 a0h = *(const bf16x8*)&A_sh[IA(mt0,0,ks,l)];
        bf16x8 a0m = *(const bf16x8*)&A_sh[IA(mt0,1,ks,l)];
        bf16x8 a0l = *(const bf16x8*)&A_sh[IA(mt0,2,ks,l)];
        bf16x8 a1h = *(const bf16x8*)&A_sh[IA(mt1,0,ks,l)];
        bf16x8 a1m = *(const bf16x8*)&A_sh[IA(mt1,1,ks,l)];
        bf16x8 a1l = *(const bf16x8*)&A_sh[IA(mt1,2,ks,l)];
        {   // cf = 0
            bf16x8 bh = *(const bf16x8*)&curB[IB(0,cst0,l)];
            bf16x8 bm = *(const bf16x8*)&curB[IB(1,cst0,l)];
            bf16x8 bl = *(const bf16x8*)&curB[IB(2,cst0,l)];
            acc00 = __builtin_amdgcn_mfma_f32_32x32x16_bf16(a0h,bh,acc00,0,0,0);
            acc00 = __builtin_amdgcn_mfma_f32_32x32x16_bf16(a0h,bm,acc00,0,0,0);
            acc00 = __builtin_amdgcn_mfma_f32_32x32x16_bf16(a0m,bh,acc00,0,0,0);
            acc00 = __builtin_amdgcn_mfma_f32_32x32x16_bf16(a0m,bm,acc00,0,0,0);
            acc00 = __builtin_amdgcn_mfma_f32_32x32x16_bf16(a0h,bl,acc00,0,0,0);
            acc00 = __builtin_amdgcn_mfma_f32_32x32x16_bf16(a0l,bh,acc00,0,0,0);
            acc10 = __builtin_amdgcn_mfma_f32_32x32x16_bf16(a1h,bh,acc10,0,0,0);
            acc10 = __builtin_amdgcn_mfma_f32_32x32x16_bf16(a1h,bm,acc10,0,0,0);
            acc10 = __builtin_amdgcn_mfma_f32_32x32x16_bf16(a1m,bh,acc10,0,0,0);
            acc10 = __builtin_amdgcn_mfma_f32_32x32x16_bf16(a1m,bm,acc10,0,0,0);
            acc10 = __builtin_amdgcn_mfma_f32_32x32x16_bf16(a1h,bl,acc10,0,0,0);
            acc10 = __builtin_amdgcn_mfma_f32_32x32x16_bf16(a1l,bh,acc10,0,0,0);
        }
        {   // cf = 1
            bf16x8 bh = *(const bf16x8*)&curB[IB(0,cst1,l)];
            bf16x8 bm = *(const bf16x8*)&curB[IB(1,cst1,l)];
            bf16x8 bl = *(const bf16x8*)&curB[IB(2,cst1,l)];
            acc01 = __builtin_amdgcn_mfma_f32_32x32x16_bf16(a0h,bh,acc01,0,0,0);
            acc01 = __builtin_amdgcn_mfma_f32_32x32x16_bf16(a0h,bm,acc01,0,0,0);
            acc01 = __builtin_amdgcn_mfma_f32_32x32x16_bf16(a0m,bh,acc01,0,0,0);
            acc01 = __builtin_amdgcn_mfma_f32_32x32x16_bf16(a0m,bm,acc01,0,0,0);
            acc01 = __builtin_amdgcn_mfma_f32_32x32x16_bf16(a0h,bl,acc01,0,0,0);
            acc01 = __builtin_amdgcn_mfma_f32_32x32x16_bf16(a0l,bh,acc01,0,0,0);
            acc11 = __builtin_amdgcn_mfma_f32_32x32x16_bf16(a1h,bh,acc11,0,0,0);
            acc11 = __builtin_amdgcn_mfma_f32_32x32x16_bf16(a1h,bm,acc11,0,0,0);
            acc11 = __builtin_amdgcn_mfma_f32_32x32x16_bf16(a1m,bh,acc11,0,0,0);
            acc11 = __builtin_amdgcn_mfma_f32_32x32x16_bf16(a1m,bm,acc11,0,0,0);
            acc11 = __builtin_amdgcn_mfma_f32_32x32x16_bf16(a1h,bl,acc11,0,0,0);
            acc11 = __builtin_amdgcn_mfma_f32_32x32x16_bf16(a1l,bh,acc11,0,0,0);
        }

        // convert + write next stage into the other buffer
        if (s < 63) {
            short* nxtB = (s & 1) ? B0_sh : B1_sh;
            float vals[8] = {e0n.x,e0n.y,e0n.z,e0n.w,e1n.x,e1n.y,e1n.z,e1n.w};
            short hh[8], mm_[8], ll[8];
            #pragma unroll
            for (int i = 0; i < 8; ++i) split3(vals[i], hh[i], mm_[i], ll[i]);
            const int cst = (t >> 1) >> 5, lb_ = ((t >> 1) & 31) + ((t & 1) << 5);
            bf16x8 H, M, L;
            #pragma unroll
            for (int i = 0; i < 8; ++i) { H[i]=hh[i]; M[i]=mm_[i]; L[i]=ll[i]; }
            *(bf16x8*)&nxtB[IB(0,cst,lb_)] = H;
            *(bf16x8*)&nxtB[IB(1,cst,lb_)] = M;
            *(bf16x8*)&nxtB[IB(2,cst,lb_)] = L;
        }
        __syncthreads();

        if (ks == 7) {   // end of c-tile: dump scores (4 phases of 64 cols) + scan
            #pragma unroll
            for (int p = 0; p < 4; ++p) {
                if ((wc & 1) == (p & 1)) {
                    const int cf = p >> 1;
                    const int cc = ((wc >> 1) << 5) + (l & 31);
                    const int cg = ct*256 + wc*64 + cf*32 + (l & 31);
                    const float en = enorm_g[cg];
                    const int rb = wm*64 + 4*(l >> 5);
                    if (cf == 0) {
                        #pragma unroll
                        for (int r = 0; r < 16; ++r) {
                            const int ro = rb + (r & 3) + 8*(r >> 2);
                            S_sh[ro*68 + cc]      = fmaf(2.f, acc00[r], -en);
                            S_sh[(ro+32)*68 + cc] = fmaf(2.f, acc10[r], -en);
                        }
                    } else {
                        #pragma unroll
                        for (int r = 0; r < 16; ++r) {
                            const int ro = rb + (r & 3) + 8*(r >> 2);
                            S_sh[ro*68 + cc]      = fmaf(2.f, acc01[r], -en);
                            S_sh[(ro+32)*68 + cc] = fmaf(2.f, acc11[r], -en);
                        }
                    }
                }
                __syncthreads();
                {   // scan: thread = (row, quarter); index-aware tie-break = np first-occurrence
                    const int row = t >> 2, qq = t & 3;
                    const int wcof = ((qq >> 1) << 1) | (p & 1);
                    const int cb = ct*256 + wcof*64 + (p >> 1)*32 + (qq & 1)*16;
                    const float* Sr = &S_sh[row*68 + qq*16];
                    #pragma unroll
                    for (int u = 0; u < 4; ++u) {
                        float4 sv = *(const float4*)(Sr + 4*u);
                        const int c0 = cb + 4*u;
                        if (sv.x > bv || (sv.x == bv && c0   < bi)) { bv = sv.x; bi = c0;   }
                        if (sv.y > bv || (sv.y == bv && c0+1 < bi)) { bv = sv.y; bi = c0+1; }
                        if (sv.z > bv || (sv.z == bv && c0+2 < bi)) { bv = sv.z; bi = c0+2; }
                        if (sv.w > bv || (sv.w == bv && c0+3 < bi)) { bv = sv.w; bi = c0+3; }
                    }
                }
                __syncthreads();
            }
            #pragma unroll
            for (int r = 0; r < 16; ++r) { acc00[r]=0.f; acc01[r]=0.f; acc10[r]=0.f; acc11[r]=0.f; }
        }
    }

    // ---- final per-row reduce over 4 quarter-threads (B0 dead: last read s=62) ----
    float* rv = (float*)B0_sh;
    int*   ri = (int*)B0_sh + 512;
    rv[(t >> 2)*4 + (t & 3)] = bv;
    ri[(t >> 2)*4 + (t & 3)] = bi;
    __syncthreads();
    if (t < 128) {
        float fv = rv[t*4]; int fi = ri[t*4];
        #pragma unroll
        for (int u = 1; u < 4; ++u) {
            float v2 = rv[t*4+u]; int i2 = ri[t*4+u];
            if (v2 > fv || (v2 == fv && i2 < fi)) { fv = v2; fi = i2; }
        }
        out[OFF_IND + (size_t)(n0 + t) * Gn + g] = (float)fi;
    }
}

// per-code gather: one wave per (g,c). Ballot-scan ind (L2-hot, 256 KB),
// cooperatively accumulate matching x rows (float2/lane, coalesced).
// Replaces 8.4M global fp32 atomics (R10's 449 us wall) with zero atomics.
// Deterministic: ascending token order. Writes new_cluster_size + new_embed_avg.
__launch_bounds__(256)
__global__ void vq_code(const float* __restrict__ x,
                        const float* __restrict__ cs_in,
                        const float* __restrict__ eavg,
                        float* __restrict__ out) {
    const int t = threadIdx.x;
    const int lane = t & 63;
    const int wv = (blockIdx.x << 2) + (t >> 6);   // 0..8191
    const int g = wv >> 11, c = wv & (Cn - 1);
    const float* indp = out + OFF_IND;
    const float* xg = x + g * DGn + lane * 2;
    float ax = 0.f, ay = 0.f;
    int cnt = 0;
    for (int chunk = 0; chunk < Nn / 64; ++chunk) {
        const int n = (chunk << 6) + lane;
        const int iv = (int)indp[(size_t)n * Gn + g];
        unsigned long long m = __ballot(iv == c);
        cnt += __popcll(m);
        while (m) {
            const int b = __ffsll((unsigned long long)m) - 1;
            const int tok = (chunk << 6) + b;
            float2 v = *(const float2*)(xg + (size_t)tok * Dn);
            ax += v.x; ay += v.y;
            m &= (m - 1);
        }
    }
    const int gc = g * Cn + c;
    if (lane == 0) out[OFF_CS + gc] = fmaf(0.2f, (float)cnt, 0.8f * cs_in[gc]);
    const float* ea = eavg + (size_t)gc * DGn + lane * 2;
    float* ao = out + OFF_AVG + (size_t)gc * DGn + lane * 2;
    ao[0] = fmaf(0.2f, ax, 0.8f * ea[0]);
    ao[1] = fmaf(0.2f, ay, 0.8f * ea[1]);
}

// quantize_st + commit loss (pure streaming; no AVG atomics anymore).
__global__ void vq_scatterQ(const float* __restrict__ x,
                            const float* __restrict__ embed,
                            float* __restrict__ out) {
    const int t = threadIdx.x;
    const int r = blockIdx.x * 8 + (t >> 5);   // row id 0..65535 = (n,g)
    const int lane32 = t & 31;
    const int n = r >> 2, g = r & 3;
    const int ci = (int)out[OFF_IND + (size_t)n * Gn + g];
    const int d = lane32 * 4;
    const float* xr = x + (size_t)n * Dn + g * DGn + d;
    const float* er = embed + ((size_t)g * Cn + ci) * DGn + d;
    float4 xv = *(const float4*)xr;
    float4 qv = *(const float4*)er;
    float4 o;
    o.x = xv.x + (qv.x - xv.x); o.y = xv.y + (qv.y - xv.y);
    o.z = xv.z + (qv.z - xv.z); o.w = xv.w + (qv.w - xv.w);
    *(float4*)(out + OFF_Q + (size_t)n * Dn + g * DGn + d) = o;
    float dx = qv.x - xv.x, dy = qv.y - xv.y, dz = qv.z - xv.z, dw = qv.w - xv.w;
    float ll = dx*dx + dy*dy + dz*dz + dw*dw;
    #pragma unroll
    for (int off = 32; off; off >>= 1) ll += __shfl_xor(ll, off, 64);
    if ((t & 63) == 0) atomicAdd(&out[OFF_LOSS], ll);
}

// per-g: total, laplace smoothing, new_embed = avg/smoothed; scale loss
__global__ void vq_finalize(float* __restrict__ out) {
    const int g = blockIdx.x >> 5;
    const int slice = blockIdx.x & 31;
    const int t = threadIdx.x;
    __shared__ float red[256];
    const float* ncs = out + OFF_CS + g * Cn;
    float s = 0.f;
    for (int c = t; c < Cn; c += 256) s += ncs[c];
    red[t] = s;
    __syncthreads();
    for (int w = 128; w; w >>= 1) {
        if (t < w) red[t] += red[t + w];
        __syncthreads();
    }
    float total = red[0];
    float denom = total + Cn * 1e-5f;
    const float* avg = out + OFF_AVG + (size_t)g * Cn * DGn;
    float* embo = out + OFF_EMB + (size_t)g * Cn * DGn;
    for (int u = 0; u < 32; ++u) {
        int e = slice * 8192 + u * 256 + t;
        int c = e >> 7;
        float sm = (ncs[c] + 1e-5f) / denom * total;
        embo[e] = avg[e] / sm;
    }
    if (blockIdx.x == 0 && t == 0) out[OFF_LOSS] *= (1.0f / 8388608.0f);
}

extern "C" void kernel_launch(void* const* d_in, const int* in_sizes, int n_in,
                              void* d_out, int out_size, void* d_ws, size_t ws_size,
                              hipStream_t stream) {
    const float* x    = (const float*)d_in[0];
    const float* emb  = (const float*)d_in[1];
    const float* cs   = (const float*)d_in[2];
    const float* eavg = (const float*)d_in[3];
    float* out = (float*)d_out;

    hipLaunchKernelGGL(vq_enorm,    dim3(2048), dim3(256), 0, stream, emb, out);
    hipLaunchKernelGGL(vq_main,     dim3(512),  dim3(512), 0, stream, x, emb, out);
    hipLaunchKernelGGL(vq_code,     dim3(2048), dim3(256), 0, stream, x, cs, eavg, out);
    hipLaunchKernelGGL(vq_scatterQ, dim3(8192), dim3(256), 0, stream, x, emb, out);
    hipLaunchKernelGGL(vq_finalize, dim3(128),  dim3(256), 0, stream, out);
}

// Round 12
// 561.026 us; speedup vs baseline: 1.7171x; 1.7171x over previous
//
#include <hip/hip_runtime.h>

// Problem dims (fixed by the reference setup)
#define Bn 8
#define Sn 2048
#define Dn 512
#define Gn 4
#define Cn 2048
#define DGn 128
#define Nn 16384  // B*S

// d_out layout (flat fp32, reference return order)
#define OFF_Q    0u        // quantize_st  [8,2048,512]  = 8388608
#define OFF_IND  8388608u  // ind_out      [8,2048,4]    = 65536 (float-encoded ints)
#define OFF_LOSS 8454144u  // commit_loss  scalar
#define OFF_CS   8454145u  // new_cluster_size [4,2048]  = 8192
#define OFF_AVG  8462337u  // new_embed_avg [4,2048,128] = 1048576
#define OFF_EMB  9510913u  // new_embed     [4,2048,128] = 1048576 (first 8192 hold ||E||^2 until finalize)

typedef __attribute__((ext_vector_type(8)))  short bf16x8;
typedef __attribute__((ext_vector_type(16))) float f32x16;

// fp32 -> bf16 bits, round-to-nearest-even
__device__ __forceinline__ unsigned bfbits(float x) {
    unsigned u = __float_as_uint(x);
    return (u + 0x7FFFu + ((u >> 16) & 1u)) & 0xFFFF0000u;
}
// exact-ish 3-way bf16 decomposition: a = h + m + l + O(2^-27 |a|)
__device__ __forceinline__ void split3(float a, short &sh, short &sm, short &sl) {
    unsigned hb = bfbits(a); float hf = __uint_as_float(hb);
    float r  = a - hf;                 // exact (Sterbenz)
    unsigned mb = bfbits(r); float mf = __uint_as_float(mb);
    float r2 = r - mf;                 // exact
    unsigned lb = bfbits(r2);
    sh = (short)(hb >> 16); sm = (short)(mb >> 16); sl = (short)(lb >> 16);
}

// one wave per code row: ||E[g,c]||^2 -> stash at OFF_EMB (overwritten by finalize).
// Also zeroes the loss scalar.
__global__ void vq_enorm(const float* __restrict__ embed,
                         float* __restrict__ out) {
    int gid  = blockIdx.x * 256 + threadIdx.x;
    int wave = gid >> 6;
    int lane = gid & 63;
    if (gid == 0) out[OFF_LOSS] = 0.0f;
    const float* row = embed + (size_t)wave * DGn;
    float a = row[lane], b = row[lane + 64];
    float v = fmaf(a, a, b * b);
    #pragma unroll
    for (int off = 32; off; off >>= 1) v += __shfl_xor(v, off, 64);
    if (lane == 0) out[OFF_EMB + wave] = v;
}

// frag-layout LDS indices (units: shorts; each frag slot = 16B = 8 bf16)
#define IA(mt,v,ks,lane) (((((mt)*3+(v))*8+(ks))*64+(lane))*8)
#define IB(v,cst,lane)   ((((v)*8+(cst))*64+(lane))*8)

// MFMA main (verified R9-R11): block = (g, 128-token tile). 512 thr = 8 waves
// (2m x 4c), wave = 64m x 64c via 2x2 mfma_f32_32x32x16_bf16 frags. bf16
// split-3, 6 passes/K-step -> dot exact to ~2^-27. c swept in 8 tiles of 256.
__launch_bounds__(512, 1)
__global__ void vq_main(const float* __restrict__ x,
                        const float* __restrict__ embed,
                        float* __restrict__ out) {
    __shared__ short A_sh[49152];   // [4 mt][3 v][8 ks][64 lane][8] = 96 KB
    __shared__ short B0_sh[12288];  // [3 v][8 cst][64 lane][8]     = 24 KB
    __shared__ float S_sh[8704];    // scores [128][68]              = 34 KB
    short* const B1_sh = (short*)S_sh;  // B double-buffer aliases S

    const int t  = threadIdx.x;
    const int l  = t & 63;
    const int w  = t >> 6;
    const int wm = w >> 2, wc = w & 3;
    const int g  = blockIdx.x >> 7;
    const int n0 = (blockIdx.x & 127) * 128;

    const float* eg = embed + (size_t)g * Cn * DGn;
    const float* enorm_g = out + OFF_EMB + g * Cn;

    // ---- stage A (128m x 128k, 3 versions) directly in frag layout ----
    {
        const int m  = t >> 2, q = t & 3;
        const int mt = m >> 5;
        const float* xr = x + (size_t)(n0 + m) * Dn + g * DGn;
        #pragma unroll
        for (int j = 0; j < 8; ++j) {
            const int k = q * 32 + j * 4;
            float4 v = *(const float4*)(xr + k);
            short h0,h1,h2,h3, p0,p1,p2,p3, q0,q1,q2,q3;
            split3(v.x, h0, p0, q0); split3(v.y, h1, p1, q1);
            split3(v.z, h2, p2, q2); split3(v.w, h3, p3, q3);
            const int lane_ = (m & 31) + ((k >> 3) & 1) * 32;
            const int ks = k >> 4, sl0 = k & 7;    // sl0 in {0,4}
            short4 hv; hv.x=h0; hv.y=h1; hv.z=h2; hv.w=h3;
            short4 mv; mv.x=p0; mv.y=p1; mv.z=p2; mv.w=p3;
            short4 lv; lv.x=q0; lv.y=q1; lv.z=q2; lv.w=q3;
            *(short4*)&A_sh[IA(mt,0,ks,lane_) + sl0] = hv;
            *(short4*)&A_sh[IA(mt,1,ks,lane_) + sl0] = mv;
            *(short4*)&A_sh[IA(mt,2,ks,lane_) + sl0] = lv;
        }
    }
    // ---- prologue: stage B (ct=0, ks=0) into B0 ----
    {
        const float* er = eg + (size_t)(t >> 1) * DGn + (t & 1) * 8;
        float4 e0 = *(const float4*)(er);
        float4 e1 = *(const float4*)(er + 4);
        float vals[8] = {e0.x,e0.y,e0.z,e0.w,e1.x,e1.y,e1.z,e1.w};
        short hh[8], mm_[8], ll[8];
        #pragma unroll
        for (int i = 0; i < 8; ++i) split3(vals[i], hh[i], mm_[i], ll[i]);
        const int cst = (t >> 1) >> 5, lb_ = ((t >> 1) & 31) + ((t & 1) << 5);
        bf16x8 H, M, L;
        #pragma unroll
        for (int i = 0; i < 8; ++i) { H[i]=hh[i]; M[i]=mm_[i]; L[i]=ll[i]; }
        *(bf16x8*)&B0_sh[IB(0,cst,lb_)] = H;
        *(bf16x8*)&B0_sh[IB(1,cst,lb_)] = M;
        *(bf16x8*)&B0_sh[IB(2,cst,lb_)] = L;
    }
    __syncthreads();

    f32x16 acc00, acc01, acc10, acc11;  // acc[mf][cf]
    #pragma unroll
    for (int r = 0; r < 16; ++r) { acc00[r]=0.f; acc01[r]=0.f; acc10[r]=0.f; acc11[r]=0.f; }

    float bv = -3.4e38f; int bi = 0;    // per-thread running argmax (index-tiebreak)

    const int mt0 = wm*2, mt1 = wm*2 + 1;
    const int cst0 = wc*2, cst1 = wc*2 + 1;

    for (int s = 0; s < 64; ++s) {       // s = ct*8 + ks; ct-tile = 256 c
        const int ct = s >> 3, ks = s & 7;
        const short* curB = (s & 1) ? B1_sh : B0_sh;

        // T14: issue next-stage global loads before compute
        float4 e0n, e1n;
        if (s < 63) {
            const int s1 = s + 1, ct1 = s1 >> 3, ks1 = s1 & 7;
            const float* er = eg + (size_t)(ct1*256 + (t >> 1)) * DGn + ks1*16 + (t & 1)*8;
            e0n = *(const float4*)(er);
            e1n = *(const float4*)(er + 4);
        }

        bf16x8 a0h = *(const bf16x8*)&A_sh[IA(mt0,0,ks,l)];
        bf16x8 a0m = *(const bf16x8*)&A_sh[IA(mt0,1,ks,l)];
        bf16x8 a0l = *(const bf16x8*)&A_sh[IA(mt0,2,ks,l)];
        bf16x8 a1h = *(const bf16x8*)&A_sh[IA(mt1,0,ks,l)];
        bf16x8 a1m = *(const bf16x8*)&A_sh[IA(mt1,1,ks,l)];
        bf16x8 a1l = *(const bf16x8*)&A_sh[IA(mt1,2,ks,l)];
        {   // cf = 0
            bf16x8 bh = *(const bf16x8*)&curB[IB(0,cst0,l)];
            bf16x8 bm = *(const bf16x8*)&curB[IB(1,cst0,l)];
            bf16x8 bl = *(const bf16x8*)&curB[IB(2,cst0,l)];
            acc00 = __builtin_amdgcn_mfma_f32_32x32x16_bf16(a0h,bh,acc00,0,0,0);
            acc00 = __builtin_amdgcn_mfma_f32_32x32x16_bf16(a0h,bm,acc00,0,0,0);
            acc00 = __builtin_amdgcn_mfma_f32_32x32x16_bf16(a0m,bh,acc00,0,0,0);
            acc00 = __builtin_amdgcn_mfma_f32_32x32x16_bf16(a0m,bm,acc00,0,0,0);
            acc00 = __builtin_amdgcn_mfma_f32_32x32x16_bf16(a0h,bl,acc00,0,0,0);
            acc00 = __builtin_amdgcn_mfma_f32_32x32x16_bf16(a0l,bh,acc00,0,0,0);
            acc10 = __builtin_amdgcn_mfma_f32_32x32x16_bf16(a1h,bh,acc10,0,0,0);
            acc10 = __builtin_amdgcn_mfma_f32_32x32x16_bf16(a1h,bm,acc10,0,0,0);
            acc10 = __builtin_amdgcn_mfma_f32_32x32x16_bf16(a1m,bh,acc10,0,0,0);
            acc10 = __builtin_amdgcn_mfma_f32_32x32x16_bf16(a1m,bm,acc10,0,0,0);
            acc10 = __builtin_amdgcn_mfma_f32_32x32x16_bf16(a1h,bl,acc10,0,0,0);
            acc10 = __builtin_amdgcn_mfma_f32_32x32x16_bf16(a1l,bh,acc10,0,0,0);
        }
        {   // cf = 1
            bf16x8 bh = *(const bf16x8*)&curB[IB(0,cst1,l)];
            bf16x8 bm = *(const bf16x8*)&curB[IB(1,cst1,l)];
            bf16x8 bl = *(const bf16x8*)&curB[IB(2,cst1,l)];
            acc01 = __builtin_amdgcn_mfma_f32_32x32x16_bf16(a0h,bh,acc01,0,0,0);
            acc01 = __builtin_amdgcn_mfma_f32_32x32x16_bf16(a0h,bm,acc01,0,0,0);
            acc01 = __builtin_amdgcn_mfma_f32_32x32x16_bf16(a0m,bh,acc01,0,0,0);
            acc01 = __builtin_amdgcn_mfma_f32_32x32x16_bf16(a0m,bm,acc01,0,0,0);
            acc01 = __builtin_amdgcn_mfma_f32_32x32x16_bf16(a0h,bl,acc01,0,0,0);
            acc01 = __builtin_amdgcn_mfma_f32_32x32x16_bf16(a0l,bh,acc01,0,0,0);
            acc11 = __builtin_amdgcn_mfma_f32_32x32x16_bf16(a1h,bh,acc11,0,0,0);
            acc11 = __builtin_amdgcn_mfma_f32_32x32x16_bf16(a1h,bm,acc11,0,0,0);
            acc11 = __builtin_amdgcn_mfma_f32_32x32x16_bf16(a1m,bh,acc11,0,0,0);
            acc11 = __builtin_amdgcn_mfma_f32_32x32x16_bf16(a1m,bm,acc11,0,0,0);
            acc11 = __builtin_amdgcn_mfma_f32_32x32x16_bf16(a1h,bl,acc11,0,0,0);
            acc11 = __builtin_amdgcn_mfma_f32_32x32x16_bf16(a1l,bh,acc11,0,0,0);
        }

        // convert + write next stage into the other buffer
        if (s < 63) {
            short* nxtB = (s & 1) ? B0_sh : B1_sh;
            float vals[8] = {e0n.x,e0n.y,e0n.z,e0n.w,e1n.x,e1n.y,e1n.z,e1n.w};
            short hh[8], mm_[8], ll[8];
            #pragma unroll
            for (int i = 0; i < 8; ++i) split3(vals[i], hh[i], mm_[i], ll[i]);
            const int cst = (t >> 1) >> 5, lb_ = ((t >> 1) & 31) + ((t & 1) << 5);
            bf16x8 H, M, L;
            #pragma unroll
            for (int i = 0; i < 8; ++i) { H[i]=hh[i]; M[i]=mm_[i]; L[i]=ll[i]; }
            *(bf16x8*)&nxtB[IB(0,cst,lb_)] = H;
            *(bf16x8*)&nxtB[IB(1,cst,lb_)] = M;
            *(bf16x8*)&nxtB[IB(2,cst,lb_)] = L;
        }
        __syncthreads();

        if (ks == 7) {   // end of c-tile: dump scores (4 phases of 64 cols) + scan
            #pragma unroll
            for (int p = 0; p < 4; ++p) {
                if ((wc & 1) == (p & 1)) {
                    const int cf = p >> 1;
                    const int cc = ((wc >> 1) << 5) + (l & 31);
                    const int cg = ct*256 + wc*64 + cf*32 + (l & 31);
                    const float en = enorm_g[cg];
                    const int rb = wm*64 + 4*(l >> 5);
                    if (cf == 0) {
                        #pragma unroll
                        for (int r = 0; r < 16; ++r) {
                            const int ro = rb + (r & 3) + 8*(r >> 2);
                            S_sh[ro*68 + cc]      = fmaf(2.f, acc00[r], -en);
                            S_sh[(ro+32)*68 + cc] = fmaf(2.f, acc10[r], -en);
                        }
                    } else {
                        #pragma unroll
                        for (int r = 0; r < 16; ++r) {
                            const int ro = rb + (r & 3) + 8*(r >> 2);
                            S_sh[ro*68 + cc]      = fmaf(2.f, acc01[r], -en);
                            S_sh[(ro+32)*68 + cc] = fmaf(2.f, acc11[r], -en);
                        }
                    }
                }
                __syncthreads();
                {   // scan: thread = (row, quarter); index-aware tie-break = np first-occurrence
                    const int row = t >> 2, qq = t & 3;
                    const int wcof = ((qq >> 1) << 1) | (p & 1);
                    const int cb = ct*256 + wcof*64 + (p >> 1)*32 + (qq & 1)*16;
                    const float* Sr = &S_sh[row*68 + qq*16];
                    #pragma unroll
                    for (int u = 0; u < 4; ++u) {
                        float4 sv = *(const float4*)(Sr + 4*u);
                        const int c0 = cb + 4*u;
                        if (sv.x > bv || (sv.x == bv && c0   < bi)) { bv = sv.x; bi = c0;   }
                        if (sv.y > bv || (sv.y == bv && c0+1 < bi)) { bv = sv.y; bi = c0+1; }
                        if (sv.z > bv || (sv.z == bv && c0+2 < bi)) { bv = sv.z; bi = c0+2; }
                        if (sv.w > bv || (sv.w == bv && c0+3 < bi)) { bv = sv.w; bi = c0+3; }
                    }
                }
                __syncthreads();
            }
            #pragma unroll
            for (int r = 0; r < 16; ++r) { acc00[r]=0.f; acc01[r]=0.f; acc10[r]=0.f; acc11[r]=0.f; }
        }
    }

    // ---- final per-row reduce over 4 quarter-threads (B0 dead: last read s=62) ----
    float* rv = (float*)B0_sh;
    int*   ri = (int*)B0_sh + 512;
    rv[(t >> 2)*4 + (t & 3)] = bv;
    ri[(t >> 2)*4 + (t & 3)] = bi;
    __syncthreads();
    if (t < 128) {
        float fv = rv[t*4]; int fi = ri[t*4];
        #pragma unroll
        for (int u = 1; u < 4; ++u) {
            float v2 = rv[t*4+u]; int i2 = ri[t*4+u];
            if (v2 > fv || (v2 == fv && i2 < fi)) { fv = v2; fi = i2; }
        }
        out[OFF_IND + (size_t)(n0 + t) * Gn + g] = (float)fi;
    }
}

// per-code gather: one wave per (g,c). Ballot-scan ind (L2-hot, 256 KB),
// cooperatively accumulate matching x rows (float2/lane, coalesced).
// Zero atomics; deterministic ascending token order.
__launch_bounds__(256)
__global__ void vq_code(const float* __restrict__ x,
                        const float* __restrict__ cs_in,
                        const float* __restrict__ eavg,
                        float* __restrict__ out) {
    const int t = threadIdx.x;
    const int lane = t & 63;
    const int wv = (blockIdx.x << 2) + (t >> 6);   // 0..8191
    const int g = wv >> 11, c = wv & (Cn - 1);
    const float* indp = out + OFF_IND;
    const float* xg = x + g * DGn + lane * 2;
    float ax = 0.f, ay = 0.f;
    int cnt = 0;
    for (int chunk = 0; chunk < Nn / 64; ++chunk) {
        const int n = (chunk << 6) + lane;
        const int iv = (int)indp[(size_t)n * Gn + g];
        unsigned long long m = __ballot(iv == c);
        cnt += __popcll(m);
        while (m) {
            const int b = __ffsll((unsigned long long)m) - 1;
            const int tok = (chunk << 6) + b;
            float2 v = *(const float2*)(xg + (size_t)tok * Dn);
            ax += v.x; ay += v.y;
            m &= (m - 1);
        }
    }
    const int gc = g * Cn + c;
    if (lane == 0) out[OFF_CS + gc] = fmaf(0.2f, (float)cnt, 0.8f * cs_in[gc]);
    const float* ea = eavg + (size_t)gc * DGn + lane * 2;
    float* ao = out + OFF_AVG + (size_t)gc * DGn + lane * 2;
    ao[0] = fmaf(0.2f, ax, 0.8f * ea[0]);
    ao[1] = fmaf(0.2f, ay, 0.8f * ea[1]);
}

// quantize_st + commit loss. Grid-stride: 1024 blocks x 8 iters x 8 rows.
// R11 lesson: 32768 same-address loss atomics serialized at ~31 cyc each
// = the entire 420 us. Now: per-thread accumulate -> wave shfl reduce ->
// LDS block reduce -> ONE atomic per block (1024 total ~ 13 us, overlapped).
__launch_bounds__(256)
__global__ void vq_scatterQ(const float* __restrict__ x,
                            const float* __restrict__ embed,
                            float* __restrict__ out) {
    __shared__ float lred[4];
    const int t = threadIdx.x;
    const int lane32 = t & 31;
    const int d = lane32 * 4;
    float ll = 0.f;
    #pragma unroll
    for (int it = 0; it < 8; ++it) {
        const int r = blockIdx.x * 64 + it * 8 + (t >> 5);   // row id = (n,g)
        const int n = r >> 2, g = r & 3;
        const int ci = (int)out[OFF_IND + (size_t)n * Gn + g];
        const float* xr = x + (size_t)n * Dn + g * DGn + d;
        const float* er = embed + ((size_t)g * Cn + ci) * DGn + d;
        float4 xv = *(const float4*)xr;
        float4 qv = *(const float4*)er;
        float4 o;
        o.x = xv.x + (qv.x - xv.x); o.y = xv.y + (qv.y - xv.y);
        o.z = xv.z + (qv.z - xv.z); o.w = xv.w + (qv.w - xv.w);
        *(float4*)(out + OFF_Q + (size_t)n * Dn + g * DGn + d) = o;
        float dx = qv.x - xv.x, dy = qv.y - xv.y, dz = qv.z - xv.z, dw = qv.w - xv.w;
        ll += dx*dx + dy*dy + dz*dz + dw*dw;
    }
    #pragma unroll
    for (int off = 32; off; off >>= 1) ll += __shfl_xor(ll, off, 64);
    if ((t & 63) == 0) lred[t >> 6] = ll;
    __syncthreads();
    if (t == 0) atomicAdd(&out[OFF_LOSS], lred[0] + lred[1] + lred[2] + lred[3]);
}

// per-g: total, laplace smoothing, new_embed = avg/smoothed; scale loss
__global__ void vq_finalize(float* __restrict__ out) {
    const int g = blockIdx.x >> 5;
    const int slice = blockIdx.x & 31;
    const int t = threadIdx.x;
    __shared__ float red[256];
    const float* ncs = out + OFF_CS + g * Cn;
    float s = 0.f;
    for (int c = t; c < Cn; c += 256) s += ncs[c];
    red[t] = s;
    __syncthreads();
    for (int w = 128; w; w >>= 1) {
        if (t < w) red[t] += red[t + w];
        __syncthreads();
    }
    float total = red[0];
    float denom = total + Cn * 1e-5f;
    const float* avg = out + OFF_AVG + (size_t)g * Cn * DGn;
    float* embo = out + OFF_EMB + (size_t)g * Cn * DGn;
    for (int u = 0; u < 32; ++u) {
        int e = slice * 8192 + u * 256 + t;
        int c = e >> 7;
        float sm = (ncs[c] + 1e-5f) / denom * total;
        embo[e] = avg[e] / sm;
    }
    if (blockIdx.x == 0 && t == 0) out[OFF_LOSS] *= (1.0f / 8388608.0f);
}

extern "C" void kernel_launch(void* const* d_in, const int* in_sizes, int n_in,
                              void* d_out, int out_size, void* d_ws, size_t ws_size,
                              hipStream_t stream) {
    const float* x    = (const float*)d_in[0];
    const float* emb  = (const float*)d_in[1];
    const float* cs   = (const float*)d_in[2];
    const float* eavg = (const float*)d_in[3];
    float* out = (float*)d_out;

    hipLaunchKernelGGL(vq_enorm,    dim3(2048), dim3(256), 0, stream, emb, out);
    hipLaunchKernelGGL(vq_main,     dim3(512),  dim3(512), 0, stream, x, emb, out);
    hipLaunchKernelGGL(vq_code,     dim3(2048), dim3(256), 0, stream, x, cs, eavg, out);
    hipLaunchKernelGGL(vq_scatterQ, dim3(1024), dim3(256), 0, stream, x, emb, out);
    hipLaunchKernelGGL(vq_finalize, dim3(128),  dim3(256), 0, stream, out);
}